// Round 1
// baseline (657.469 us; speedup 1.0000x reference)
//
#include <hip/hip_runtime.h>
#include <hip/hip_bf16.h>
#include <stdint.h>

#define N_NODES 50000
#define N_EDGES 800000
#define D_IN    128
#define H_DIM   256
#define BN_EPS  1e-5f
#define LN_EPS  1e-5f

typedef float v4f __attribute__((ext_vector_type(4)));
typedef short v8s __attribute__((ext_vector_type(8)));

__device__ __forceinline__ float bflo(unsigned u){ return __uint_as_float(u << 16); }
__device__ __forceinline__ float bfhi(unsigned u){ return __uint_as_float(u & 0xffff0000u); }
__device__ __forceinline__ unsigned short f2bf(float f){
  unsigned u = __float_as_uint(f);
  u += 0x7fffu + ((u >> 16) & 1u);
  return (unsigned short)(u >> 16);
}
__device__ __forceinline__ unsigned pack2(float a, float b){
  return (unsigned)f2bf(a) | ((unsigned)f2bf(b) << 16);
}
__device__ __forceinline__ float wred(float v){
  #pragma unroll
  for (int m = 1; m < 64; m <<= 1) v += __shfl_xor(v, m, 64);
  return v;
}

// ---------------- degree / CSR ----------------
__global__ void deg_k(const int* ei, int* cnt){
  int e = blockIdx.x * 256 + threadIdx.x;
  if (e < N_EDGES) atomicAdd(&cnt[ei[N_EDGES + e]], 1);
}

__global__ void dinv_k(const int* cnt, float* dinv){
  int i = blockIdx.x * 256 + threadIdx.x;
  if (i < N_NODES) dinv[i] = rsqrtf((float)cnt[i] + 1.0f);
}

__global__ void scan_k(const int* cnt, int* offsets, int* cursor){
  __shared__ int sums[1024];
  int t = threadIdx.x;
  const int n = N_NODES;
  const int chunk = (n + 1023) >> 10;
  int base = t * chunk;
  int hi = min(base + chunk, n);
  int s = 0;
  for (int i = base; i < hi; ++i) s += cnt[i];
  sums[t] = s;
  __syncthreads();
  for (int off = 1; off < 1024; off <<= 1){
    int v = (t >= off) ? sums[t - off] : 0;
    __syncthreads();
    sums[t] += v;
    __syncthreads();
  }
  int run = sums[t] - s;  // exclusive prefix
  for (int i = base; i < hi; ++i){ offsets[i] = run; cursor[i] = run; run += cnt[i]; }
  if (t == 1023) offsets[n] = sums[1023];
}

__global__ void csr_k(const int* ei, const float* dinv, int* cursor, int* srcs, float* wts){
  int e = blockIdx.x * 256 + threadIdx.x;
  if (e >= N_EDGES) return;
  int s = ei[e], d = ei[N_EDGES + e];
  int p = atomicAdd(&cursor[d], 1);
  srcs[p] = s;
  wts[p] = dinv[s] * dinv[d];
}

// ---------------- BN0 stats over y = x*fs + fb ----------------
__global__ __launch_bounds__(256) void bn0stats_k(const float* x, const float* fs, const float* fb,
                                                  float* S, float* Q){
  int t = threadIdx.x;
  int cl = t & 31, rg = t >> 5;
  int c = cl * 4;
  float4 fs4 = *(const float4*)(fs + c);
  float4 fb4 = *(const float4*)(fb + c);
  float s0=0,s1=0,s2=0,s3=0,q0=0,q1=0,q2=0,q3=0;
  for (int row = blockIdx.x * 8 + rg; row < N_NODES; row += gridDim.x * 8){
    float4 xv = *(const float4*)(x + (size_t)row * D_IN + c);
    float v0 = xv.x * fs4.x + fb4.x;
    float v1 = xv.y * fs4.y + fb4.y;
    float v2 = xv.z * fs4.z + fb4.z;
    float v3 = xv.w * fs4.w + fb4.w;
    s0 += v0; s1 += v1; s2 += v2; s3 += v3;
    q0 += v0*v0; q1 += v1*v1; q2 += v2*v2; q3 += v3*v3;
  }
  __shared__ float red[256][8];
  red[t][0]=s0; red[t][1]=s1; red[t][2]=s2; red[t][3]=s3;
  red[t][4]=q0; red[t][5]=q1; red[t][6]=q2; red[t][7]=q3;
  __syncthreads();
  if (t < 32){
    float a[8];
    #pragma unroll
    for (int i = 0; i < 8; ++i) a[i] = red[t][i];
    for (int j = 1; j < 8; ++j)
      #pragma unroll
      for (int i = 0; i < 8; ++i) a[i] += red[t + 32*j][i];
    #pragma unroll
    for (int i = 0; i < 4; ++i){ atomicAdd(&S[t*4+i], a[i]); atomicAdd(&Q[t*4+i], a[4+i]); }
  }
}

__global__ void bn0final_k(const float* S, const float* Q, const float* fs, const float* fb,
                           const float* gg, const float* bb, float* A0, float* B0){
  int c = threadIdx.x; // 128
  float mu = S[c] * (1.0f / N_NODES);
  float var = Q[c] * (1.0f / N_NODES) - mu * mu;
  float rs = rsqrtf(var + BN_EPS);
  A0[c] = gg[c] * rs * fs[c];
  B0[c] = gg[c] * rs * (fb[c] - mu) + bb[c];
}

__global__ __launch_bounds__(256) void prepx_k(const float* x, const float* A0, const float* B0,
                                               unsigned short* xt){
  int i = blockIdx.x * 256 + threadIdx.x; // N*32 total
  int row = i >> 5; int c = (i & 31) * 4;
  float4 xv = *(const float4*)(x + (size_t)row * D_IN + c);
  float4 a = *(const float4*)(A0 + c);
  float4 b = *(const float4*)(B0 + c);
  uint2 o;
  o.x = pack2(a.x * xv.x + b.x, a.y * xv.y + b.y);
  o.y = pack2(a.z * xv.z + b.z, a.w * xv.w + b.w);
  *(uint2*)(xt + (size_t)row * D_IN + c) = o;
}

__global__ void transpose_k(const float* W, unsigned short* Wt, int R, int C){
  int i = blockIdx.x * 256 + threadIdx.x;
  if (i >= R * C) return;
  int r = i / C, c = i % C;
  Wt[c * R + r] = f2bf(W[i]);
}

// ---------------- bf16 MFMA GEMM: C[M,256] = A[M,K] @ Bt[256,K]^T ----------------
__global__ __launch_bounds__(256) void gemm_k(const unsigned short* A, const unsigned short* Bt,
                                              unsigned short* C, int M, int K){
  __shared__ __align__(16) short As[64 * 40];
  __shared__ __align__(16) short Bs[64 * 40];
  int t = threadIdx.x;
  int m0 = blockIdx.y * 64;
  int n0 = blockIdx.x * 64;
  int lr = t >> 2;
  int lk = (t & 3) << 3;
  int lane = t & 63;
  int w = t >> 6;
  int wm = (w >> 1) << 5, wn = (w & 1) << 5;
  int fr = lane & 15, quad = lane >> 4;
  v4f acc[2][2] = {};
  for (int k0 = 0; k0 < K; k0 += 32){
    __syncthreads();
    uint4 av = {0,0,0,0};
    int row = m0 + lr;
    if (row < M) av = *(const uint4*)(A + (size_t)row * K + k0 + lk);
    *(uint4*)(&As[lr * 40 + lk]) = av;
    uint4 bv = *(const uint4*)(Bt + (size_t)(n0 + lr) * K + k0 + lk);
    *(uint4*)(&Bs[lr * 40 + lk]) = bv;
    __syncthreads();
    v8s a0 = *(const v8s*)(&As[(wm + fr) * 40 + quad * 8]);
    v8s a1 = *(const v8s*)(&As[(wm + 16 + fr) * 40 + quad * 8]);
    v8s b0 = *(const v8s*)(&Bs[(wn + fr) * 40 + quad * 8]);
    v8s b1 = *(const v8s*)(&Bs[(wn + 16 + fr) * 40 + quad * 8]);
    acc[0][0] = __builtin_amdgcn_mfma_f32_16x16x32_bf16(a0, b0, acc[0][0], 0, 0, 0);
    acc[0][1] = __builtin_amdgcn_mfma_f32_16x16x32_bf16(a0, b1, acc[0][1], 0, 0, 0);
    acc[1][0] = __builtin_amdgcn_mfma_f32_16x16x32_bf16(a1, b0, acc[1][0], 0, 0, 0);
    acc[1][1] = __builtin_amdgcn_mfma_f32_16x16x32_bf16(a1, b1, acc[1][1], 0, 0, 0);
  }
  #pragma unroll
  for (int ti = 0; ti < 2; ++ti)
    #pragma unroll
    for (int tj = 0; tj < 2; ++tj)
      #pragma unroll
      for (int r = 0; r < 4; ++r){
        int row = m0 + wm + ti * 16 + quad * 4 + r;
        if (row < M){
          int col = n0 + wn + tj * 16 + fr;
          C[(size_t)row * H_DIM + col] = f2bf(acc[ti][tj][r]);
        }
      }
}

// ---------------- edge aggregation: g = relu(sum_e w*hlin[src] + dinv^2*hlin[node] + b) ----------------
__global__ __launch_bounds__(256) void agg_k(const unsigned short* hlin, const int* offsets,
                                             const int* srcs, const float* wts, const float* dinv,
                                             const float* bias, unsigned short* g){
  int lane = threadIdx.x & 63;
  int node = blockIdx.x * 4 + (threadIdx.x >> 6);
  if (node >= N_NODES) return;
  int c = lane * 4;
  float4 bb = *(const float4*)(bias + c);
  float di = dinv[node]; float dii = di * di;
  uint2 u = *(const uint2*)(hlin + (size_t)node * H_DIM + c);
  float a0 = bb.x + dii * bflo(u.x);
  float a1 = bb.y + dii * bfhi(u.x);
  float a2 = bb.z + dii * bflo(u.y);
  float a3 = bb.w + dii * bfhi(u.y);
  int e = offsets[node], e1 = offsets[node + 1];
  for (; e + 1 < e1; e += 2){
    int s0 = srcs[e], s1 = srcs[e + 1];
    float w0 = wts[e], w1 = wts[e + 1];
    uint2 ua = *(const uint2*)(hlin + (size_t)s0 * H_DIM + c);
    uint2 ub = *(const uint2*)(hlin + (size_t)s1 * H_DIM + c);
    a0 += w0 * bflo(ua.x) + w1 * bflo(ub.x);
    a1 += w0 * bfhi(ua.x) + w1 * bfhi(ub.x);
    a2 += w0 * bflo(ua.y) + w1 * bflo(ub.y);
    a3 += w0 * bfhi(ua.y) + w1 * bfhi(ub.y);
  }
  if (e < e1){
    int s0 = srcs[e]; float w0 = wts[e];
    uint2 ua = *(const uint2*)(hlin + (size_t)s0 * H_DIM + c);
    a0 += w0 * bflo(ua.x); a1 += w0 * bfhi(ua.x);
    a2 += w0 * bflo(ua.y); a3 += w0 * bfhi(ua.y);
  }
  a0 = fmaxf(a0, 0.f); a1 = fmaxf(a1, 0.f); a2 = fmaxf(a2, 0.f); a3 = fmaxf(a3, 0.f);
  uint2 o; o.x = pack2(a0, a1); o.y = pack2(a2, a3);
  *(uint2*)(g + (size_t)node * H_DIM + c) = o;
}

// ---------------- column stats over g (bf16 [N,256]) ----------------
__global__ __launch_bounds__(256) void colstats_k(const unsigned short* g, float* S, float* Q){
  int t = threadIdx.x;
  int cl = t & 63, rg = t >> 6;
  int c = cl * 4;
  float s0=0,s1=0,s2=0,s3=0,q0=0,q1=0,q2=0,q3=0;
  for (int row = blockIdx.x * 4 + rg; row < N_NODES; row += gridDim.x * 4){
    uint2 u = *(const uint2*)(g + (size_t)row * H_DIM + c);
    float v0 = bflo(u.x), v1 = bfhi(u.x), v2 = bflo(u.y), v3 = bfhi(u.y);
    s0 += v0; s1 += v1; s2 += v2; s3 += v3;
    q0 += v0*v0; q1 += v1*v1; q2 += v2*v2; q3 += v3*v3;
  }
  __shared__ float red[256][8];
  red[t][0]=s0; red[t][1]=s1; red[t][2]=s2; red[t][3]=s3;
  red[t][4]=q0; red[t][5]=q1; red[t][6]=q2; red[t][7]=q3;
  __syncthreads();
  if (t < 64){
    float a[8];
    #pragma unroll
    for (int i = 0; i < 8; ++i) a[i] = red[t][i];
    for (int j = 1; j < 4; ++j)
      #pragma unroll
      for (int i = 0; i < 8; ++i) a[i] += red[t + 64*j][i];
    #pragma unroll
    for (int i = 0; i < 4; ++i){ atomicAdd(&S[t*4+i], a[i]); atomicAdd(&Q[t*4+i], a[4+i]); }
  }
}

__global__ void bnfin_k(const float* S, const float* Q, const float* gg, const float* bb,
                        float* sc, float* sh){
  int c = threadIdx.x; // 256
  float mu = S[c] * (1.0f / N_NODES);
  float var = Q[c] * (1.0f / N_NODES) - mu * mu;
  float rs = rsqrtf(var + BN_EPS);
  sc[c] = gg[c] * rs;
  sh[c] = bb[c] - gg[c] * rs * mu;
}

// ---------------- BN + LN apply (layer 1): h1 = LN(BN(g)) ----------------
__global__ __launch_bounds__(256) void apply1_k(const unsigned short* g, const float* sc, const float* sh,
                                                const float* lng, const float* lnb, unsigned short* h1){
  int lane = threadIdx.x & 63;
  int row = blockIdx.x * 4 + (threadIdx.x >> 6);
  if (row >= N_NODES) return;
  int c = lane * 4;
  uint2 u = *(const uint2*)(g + (size_t)row * H_DIM + c);
  float4 s4 = *(const float4*)(sc + c);
  float4 h4 = *(const float4*)(sh + c);
  float v0 = s4.x * bflo(u.x) + h4.x;
  float v1 = s4.y * bfhi(u.x) + h4.y;
  float v2 = s4.z * bflo(u.y) + h4.z;
  float v3 = s4.w * bfhi(u.y) + h4.w;
  float sum = wred(v0 + v1 + v2 + v3);
  float sq  = wred(v0*v0 + v1*v1 + v2*v2 + v3*v3);
  float mu = sum * (1.0f / H_DIM);
  float var = sq * (1.0f / H_DIM) - mu * mu;
  float rs = rsqrtf(var + LN_EPS);
  float4 g4 = *(const float4*)(lng + c);
  float4 b4 = *(const float4*)(lnb + c);
  float y0 = g4.x * (v0 - mu) * rs + b4.x;
  float y1 = g4.y * (v1 - mu) * rs + b4.y;
  float y2 = g4.z * (v2 - mu) * rs + b4.z;
  float y3 = g4.w * (v3 - mu) * rs + b4.w;
  uint2 o; o.x = pack2(y0, y1); o.y = pack2(y2, y3);
  *(uint2*)(h1 + (size_t)row * H_DIM + c) = o;
}

// ---------------- layer 2 apply + residual + output GEMM ----------------
__global__ __launch_bounds__(256) void apply2_k(const unsigned short* g, const float* sc, const float* sh,
                                                const float* lng, const float* lnb,
                                                const unsigned short* h1, const float* Wout,
                                                const float* bout, float* out){
  int lane = threadIdx.x & 63;
  int row = blockIdx.x * 4 + (threadIdx.x >> 6);
  if (row >= N_NODES) return;
  int c = lane * 4;
  uint2 u = *(const uint2*)(g + (size_t)row * H_DIM + c);
  float4 s4 = *(const float4*)(sc + c);
  float4 h4 = *(const float4*)(sh + c);
  float v0 = s4.x * bflo(u.x) + h4.x;
  float v1 = s4.y * bfhi(u.x) + h4.y;
  float v2 = s4.z * bflo(u.y) + h4.z;
  float v3 = s4.w * bfhi(u.y) + h4.w;
  float sum = wred(v0 + v1 + v2 + v3);
  float sq  = wred(v0*v0 + v1*v1 + v2*v2 + v3*v3);
  float mu = sum * (1.0f / H_DIM);
  float var = sq * (1.0f / H_DIM) - mu * mu;
  float rs = rsqrtf(var + LN_EPS);
  float4 g4 = *(const float4*)(lng + c);
  float4 b4 = *(const float4*)(lnb + c);
  uint2 hr = *(const uint2*)(h1 + (size_t)row * H_DIM + c);
  float y0 = g4.x * (v0 - mu) * rs + b4.x + bflo(hr.x);
  float y1 = g4.y * (v1 - mu) * rs + b4.y + bfhi(hr.x);
  float y2 = g4.z * (v2 - mu) * rs + b4.z + bflo(hr.y);
  float y3 = g4.w * (v3 - mu) * rs + b4.w + bfhi(hr.y);
  // Wout row-major [256][2]
  float4 w0 = *(const float4*)(Wout + c * 2);      // (c,0) (c,1) (c+1,0) (c+1,1)
  float4 w1 = *(const float4*)(Wout + c * 2 + 4);  // (c+2,0) (c+2,1) (c+3,0) (c+3,1)
  float o0 = y0 * w0.x + y1 * w0.z + y2 * w1.x + y3 * w1.z;
  float o1 = y0 * w0.y + y1 * w0.w + y2 * w1.y + y3 * w1.w;
  o0 = wred(o0); o1 = wred(o1);
  if (lane == 0){
    out[(size_t)row * 2 + 0] = o0 + bout[0];
    out[(size_t)row * 2 + 1] = o1 + bout[1];
  }
}

extern "C" void kernel_launch(void* const* d_in, const int* in_sizes, int n_in,
                              void* d_out, int out_size, void* d_ws, size_t ws_size,
                              hipStream_t stream) {
  const float* x    = (const float*)d_in[0];
  const int*   ei   = (const int*)d_in[1];
  const float* fs   = (const float*)d_in[2];
  const float* fb   = (const float*)d_in[3];
  const float* bn0g = (const float*)d_in[4];
  const float* bn0b = (const float*)d_in[5];
  const float* W1   = (const float*)d_in[6];
  const float* b1   = (const float*)d_in[7];
  const float* bn1g = (const float*)d_in[8];
  const float* bn1b = (const float*)d_in[9];
  const float* ln1g = (const float*)d_in[10];
  const float* ln1b = (const float*)d_in[11];
  const float* W2   = (const float*)d_in[12];
  const float* b2   = (const float*)d_in[13];
  const float* bn2g = (const float*)d_in[14];
  const float* bn2b = (const float*)d_in[15];
  const float* ln2g = (const float*)d_in[16];
  const float* ln2b = (const float*)d_in[17];
  const float* Wout = (const float*)d_in[18];
  const float* bout = (const float*)d_in[19];
  float* out = (float*)d_out;

  char* w = (char*)d_ws;
  // zeroed region (one memset): cnt + all stat sums
  int*   cnt   = (int*)(w + 0);            // 200000 B
  float* bn0S  = (float*)(w + 200000);     // 512
  float* bn0Q  = (float*)(w + 200512);     // 512
  float* S1    = (float*)(w + 201024);     // 1024
  float* Q1    = (float*)(w + 202048);     // 1024
  float* S2    = (float*)(w + 203072);     // 1024
  float* Q2    = (float*)(w + 204096);     // 1024 -> end 205120
  const size_t ZERO_BYTES = 205120;
  float* A0    = (float*)(w + 205120);     // 512
  float* B0    = (float*)(w + 205632);     // 512
  float* s1    = (float*)(w + 206144);     // 1024
  float* t1    = (float*)(w + 207168);     // 1024
  float* s2    = (float*)(w + 208192);     // 1024
  float* t2    = (float*)(w + 209216);     // 1024 -> 210240
  float* dinv  = (float*)(w + 210240);     // 200000
  int*   offs  = (int*)(w + 410240);       // 200004 -> pad to 610304
  int*   curs  = (int*)(w + 610304);       // 200000
  int*   srcs  = (int*)(w + 810304);       // 3200000
  float* wts   = (float*)(w + 4010304);    // 3200000 -> 7210304, pad to 7210496
  unsigned short* xt   = (unsigned short*)(w + 7210496);   // 12.8 MB
  unsigned short* W1t  = (unsigned short*)(w + 20010496);  // 64 KB
  unsigned short* W2t  = (unsigned short*)(w + 20076032);  // 128 KB
  unsigned short* hlin = (unsigned short*)(w + 20207104);  // 25.6 MB
  unsigned short* gbuf = (unsigned short*)(w + 45807104);  // 25.6 MB
  unsigned short* h1   = (unsigned short*)(w + 71407104);  // 25.6 MB -> 97007104 total

  (void)in_sizes; (void)n_in; (void)out_size; (void)ws_size;

  hipMemsetAsync(d_ws, 0, ZERO_BYTES, stream);

  // graph preprocessing
  deg_k<<<(N_EDGES + 255) / 256, 256, 0, stream>>>(ei, cnt);
  dinv_k<<<(N_NODES + 255) / 256, 256, 0, stream>>>(cnt, dinv);
  scan_k<<<1, 1024, 0, stream>>>(cnt, offs, curs);
  csr_k<<<(N_EDGES + 255) / 256, 256, 0, stream>>>(ei, dinv, curs, srcs, wts);

  // input transform + BN0 folded into affine, cast to bf16
  bn0stats_k<<<256, 256, 0, stream>>>(x, fs, fb, bn0S, bn0Q);
  bn0final_k<<<1, 128, 0, stream>>>(bn0S, bn0Q, fs, fb, bn0g, bn0b, A0, B0);
  prepx_k<<<(N_NODES * 32) / 256, 256, 0, stream>>>(x, A0, B0, xt);

  // weight transposes (bf16, K-inner)
  transpose_k<<<(D_IN * H_DIM + 255) / 256, 256, 0, stream>>>(W1, W1t, D_IN, H_DIM);
  transpose_k<<<(H_DIM * H_DIM + 255) / 256, 256, 0, stream>>>(W2, W2t, H_DIM, H_DIM);

  dim3 ggrid(H_DIM / 64, (N_NODES + 63) / 64);

  // ---- layer 1 ----
  gemm_k<<<ggrid, 256, 0, stream>>>(xt, W1t, hlin, N_NODES, D_IN);
  agg_k<<<(N_NODES + 3) / 4, 256, 0, stream>>>(hlin, offs, srcs, wts, dinv, b1, gbuf);
  colstats_k<<<512, 256, 0, stream>>>(gbuf, S1, Q1);
  bnfin_k<<<1, 256, 0, stream>>>(S1, Q1, bn1g, bn1b, s1, t1);
  apply1_k<<<(N_NODES + 3) / 4, 256, 0, stream>>>(gbuf, s1, t1, ln1g, ln1b, h1);

  // ---- layer 2 ----
  gemm_k<<<ggrid, 256, 0, stream>>>(h1, W2t, hlin, N_NODES, H_DIM);
  agg_k<<<(N_NODES + 3) / 4, 256, 0, stream>>>(hlin, offs, srcs, wts, dinv, b2, gbuf);
  colstats_k<<<512, 256, 0, stream>>>(gbuf, S2, Q2);
  bnfin_k<<<1, 256, 0, stream>>>(S2, Q2, bn2g, bn2b, s2, t2);
  apply2_k<<<(N_NODES + 3) / 4, 256, 0, stream>>>(gbuf, s2, t2, ln2g, ln2b, h1, Wout, bout, out);
}

// Round 2
// 562.399 us; speedup vs baseline: 1.1690x; 1.1690x over previous
//
#include <hip/hip_runtime.h>
#include <hip/hip_bf16.h>
#include <stdint.h>

#define N_NODES 50000
#define N_EDGES 800000
#define D_IN    128
#define H_DIM   256
#define BN_EPS  1e-5f
#define LN_EPS  1e-5f
#define NBLK_SCAN 196  // ceil(50000/256)

typedef float v4f __attribute__((ext_vector_type(4)));
typedef short v8s __attribute__((ext_vector_type(8)));

__device__ __forceinline__ float bflo(unsigned u){ return __uint_as_float(u << 16); }
__device__ __forceinline__ float bfhi(unsigned u){ return __uint_as_float(u & 0xffff0000u); }
__device__ __forceinline__ unsigned short f2bf(float f){
  unsigned u = __float_as_uint(f);
  u += 0x7fffu + ((u >> 16) & 1u);
  return (unsigned short)(u >> 16);
}
__device__ __forceinline__ unsigned pack2(float a, float b){
  return (unsigned)f2bf(a) | ((unsigned)f2bf(b) << 16);
}
__device__ __forceinline__ float wred(float v){
  #pragma unroll
  for (int m = 1; m < 64; m <<= 1) v += __shfl_xor(v, m, 64);
  return v;
}

// in-block (256 threads) exclusive scan of one int per thread
__device__ __forceinline__ int block_excl_scan(int v){
  int t = threadIdx.x;
  int lane = t & 63, w = t >> 6;
  int inc = v;
  #pragma unroll
  for (int m = 1; m < 64; m <<= 1){
    int o = __shfl_up(inc, m, 64);
    if (lane >= m) inc += o;
  }
  __shared__ int wsum[4];
  if (lane == 63) wsum[w] = inc;
  __syncthreads();
  int base = 0;
  #pragma unroll
  for (int j = 0; j < 4; ++j) if (j < w) base += wsum[j];
  return base + inc - v;  // exclusive
}

// ---------------- degree / CSR ----------------
__global__ void deg_k(const int* ei, int* cnt){
  int e = blockIdx.x * 256 + threadIdx.x;
  if (e < N_EDGES) atomicAdd(&cnt[ei[N_EDGES + e]], 1);
}

__global__ __launch_bounds__(256) void blocksum_k(const int* cnt, int* bsum){
  int i = blockIdx.x * 256 + threadIdx.x;
  int v = (i < N_NODES) ? cnt[i] : 0;
  #pragma unroll
  for (int m = 1; m < 64; m <<= 1) v += __shfl_xor(v, m, 64);
  __shared__ int ws[4];
  int t = threadIdx.x;
  if ((t & 63) == 0) ws[t >> 6] = v;
  __syncthreads();
  if (t == 0) bsum[blockIdx.x] = ws[0] + ws[1] + ws[2] + ws[3];
}

__global__ __launch_bounds__(256) void bscan_k(const int* bsum, int* bpre, int* offs){
  int t = threadIdx.x;
  int v = (t < NBLK_SCAN) ? bsum[t] : 0;
  int e = block_excl_scan(v);
  if (t < NBLK_SCAN) bpre[t] = e;
  if (t == 0) offs[N_NODES] = N_EDGES;
}

__global__ __launch_bounds__(256) void cscan_k(const int* cnt, const int* bpre,
                                               int* offs, int* curs, float* dinv){
  int i = blockIdx.x * 256 + threadIdx.x;
  int v = (i < N_NODES) ? cnt[i] : 0;
  int e = block_excl_scan(v) + bpre[blockIdx.x];
  if (i < N_NODES){
    offs[i] = e; curs[i] = e;
    dinv[i] = rsqrtf((float)v + 1.0f);
  }
}

__global__ void csr_k(const int* ei, const float* dinv, int* cursor, int* srcs, float* wts){
  int e = blockIdx.x * 256 + threadIdx.x;
  if (e >= N_EDGES) return;
  int s = ei[e], d = ei[N_EDGES + e];
  int p = atomicAdd(&cursor[d], 1);
  srcs[p] = s;
  wts[p] = dinv[s] * dinv[d];
}

// ---------------- BN0 stats over y = x*fs + fb ----------------
__global__ __launch_bounds__(256) void bn0stats_k(const float* x, const float* fs, const float* fb,
                                                  float* S, float* Q){
  int t = threadIdx.x;
  int cl = t & 31, rg = t >> 5;
  int c = cl * 4;
  float4 fs4 = *(const float4*)(fs + c);
  float4 fb4 = *(const float4*)(fb + c);
  float s0=0,s1=0,s2=0,s3=0,q0=0,q1=0,q2=0,q3=0;
  for (int row = blockIdx.x * 8 + rg; row < N_NODES; row += gridDim.x * 8){
    float4 xv = *(const float4*)(x + (size_t)row * D_IN + c);
    float v0 = xv.x * fs4.x + fb4.x;
    float v1 = xv.y * fs4.y + fb4.y;
    float v2 = xv.z * fs4.z + fb4.z;
    float v3 = xv.w * fs4.w + fb4.w;
    s0 += v0; s1 += v1; s2 += v2; s3 += v3;
    q0 += v0*v0; q1 += v1*v1; q2 += v2*v2; q3 += v3*v3;
  }
  __shared__ float red[256][8];
  red[t][0]=s0; red[t][1]=s1; red[t][2]=s2; red[t][3]=s3;
  red[t][4]=q0; red[t][5]=q1; red[t][6]=q2; red[t][7]=q3;
  __syncthreads();
  if (t < 32){
    float a[8];
    #pragma unroll
    for (int i = 0; i < 8; ++i) a[i] = red[t][i];
    for (int j = 1; j < 8; ++j)
      #pragma unroll
      for (int i = 0; i < 8; ++i) a[i] += red[t + 32*j][i];
    #pragma unroll
    for (int i = 0; i < 4; ++i){ atomicAdd(&S[t*4+i], a[i]); atomicAdd(&Q[t*4+i], a[4+i]); }
  }
}

__global__ void bn0final_k(const float* S, const float* Q, const float* fs, const float* fb,
                           const float* gg, const float* bb, float* A0, float* B0){
  int c = threadIdx.x; // 128
  float mu = S[c] * (1.0f / N_NODES);
  float var = Q[c] * (1.0f / N_NODES) - mu * mu;
  float rs = rsqrtf(var + BN_EPS);
  A0[c] = gg[c] * rs * fs[c];
  B0[c] = gg[c] * rs * (fb[c] - mu) + bb[c];
}

__global__ __launch_bounds__(256) void prepx_k(const float* x, const float* A0, const float* B0,
                                               unsigned short* xt){
  int i = blockIdx.x * 256 + threadIdx.x; // N*32 total
  int row = i >> 5; int c = (i & 31) * 4;
  float4 xv = *(const float4*)(x + (size_t)row * D_IN + c);
  float4 a = *(const float4*)(A0 + c);
  float4 b = *(const float4*)(B0 + c);
  uint2 o;
  o.x = pack2(a.x * xv.x + b.x, a.y * xv.y + b.y);
  o.y = pack2(a.z * xv.z + b.z, a.w * xv.w + b.w);
  *(uint2*)(xt + (size_t)row * D_IN + c) = o;
}

__global__ void transpose2_k(const float* W1, const float* W2,
                             unsigned short* W1t, unsigned short* W2t){
  int i = blockIdx.x * 256 + threadIdx.x;
  if (i < D_IN * H_DIM){
    int r = i / H_DIM, c = i % H_DIM;
    W1t[c * D_IN + r] = f2bf(W1[i]);
  }
  if (i < H_DIM * H_DIM){
    int r = i / H_DIM, c = i % H_DIM;
    W2t[c * H_DIM + r] = f2bf(W2[i]);
  }
}

// ---------------- bf16 MFMA GEMM: C[M,256] = A[M,K] @ Bt[256,K]^T ----------------
__global__ __launch_bounds__(256) void gemm_k(const unsigned short* A, const unsigned short* Bt,
                                              unsigned short* C, int M, int K){
  __shared__ __align__(16) short As[64 * 40];
  __shared__ __align__(16) short Bs[64 * 40];
  int t = threadIdx.x;
  int m0 = blockIdx.y * 64;
  int n0 = blockIdx.x * 64;
  int lr = t >> 2;
  int lk = (t & 3) << 3;
  int lane = t & 63;
  int w = t >> 6;
  int wm = (w >> 1) << 5, wn = (w & 1) << 5;
  int fr = lane & 15, quad = lane >> 4;
  v4f acc[2][2] = {};
  for (int k0 = 0; k0 < K; k0 += 32){
    __syncthreads();
    uint4 av = {0,0,0,0};
    int row = m0 + lr;
    if (row < M) av = *(const uint4*)(A + (size_t)row * K + k0 + lk);
    *(uint4*)(&As[lr * 40 + lk]) = av;
    uint4 bv = *(const uint4*)(Bt + (size_t)(n0 + lr) * K + k0 + lk);
    *(uint4*)(&Bs[lr * 40 + lk]) = bv;
    __syncthreads();
    v8s a0 = *(const v8s*)(&As[(wm + fr) * 40 + quad * 8]);
    v8s a1 = *(const v8s*)(&As[(wm + 16 + fr) * 40 + quad * 8]);
    v8s b0 = *(const v8s*)(&Bs[(wn + fr) * 40 + quad * 8]);
    v8s b1 = *(const v8s*)(&Bs[(wn + 16 + fr) * 40 + quad * 8]);
    acc[0][0] = __builtin_amdgcn_mfma_f32_16x16x32_bf16(a0, b0, acc[0][0], 0, 0, 0);
    acc[0][1] = __builtin_amdgcn_mfma_f32_16x16x32_bf16(a0, b1, acc[0][1], 0, 0, 0);
    acc[1][0] = __builtin_amdgcn_mfma_f32_16x16x32_bf16(a1, b0, acc[1][0], 0, 0, 0);
    acc[1][1] = __builtin_amdgcn_mfma_f32_16x16x32_bf16(a1, b1, acc[1][1], 0, 0, 0);
  }
  #pragma unroll
  for (int ti = 0; ti < 2; ++ti)
    #pragma unroll
    for (int tj = 0; tj < 2; ++tj)
      #pragma unroll
      for (int r = 0; r < 4; ++r){
        int row = m0 + wm + ti * 16 + quad * 4 + r;
        if (row < M){
          int col = n0 + wn + tj * 16 + fr;
          C[(size_t)row * H_DIM + col] = f2bf(acc[ti][tj][r]);
        }
      }
}

// ---------------- edge aggregation: g = relu(sum_e w*hlin[src] + dinv^2*hlin[node] + b) ----------------
__global__ __launch_bounds__(256) void agg_k(const unsigned short* hlin, const int* offsets,
                                             const int* srcs, const float* wts, const float* dinv,
                                             const float* bias, unsigned short* g){
  int lane = threadIdx.x & 63;
  int node = blockIdx.x * 4 + (threadIdx.x >> 6);
  if (node >= N_NODES) return;
  int c = lane * 4;
  float4 bb = *(const float4*)(bias + c);
  float di = dinv[node]; float dii = di * di;
  uint2 u = *(const uint2*)(hlin + (size_t)node * H_DIM + c);
  float a0 = bb.x + dii * bflo(u.x);
  float a1 = bb.y + dii * bfhi(u.x);
  float a2 = bb.z + dii * bflo(u.y);
  float a3 = bb.w + dii * bfhi(u.y);
  int e = offsets[node], e1 = offsets[node + 1];
  for (; e + 1 < e1; e += 2){
    int s0 = srcs[e], s1 = srcs[e + 1];
    float w0 = wts[e], w1 = wts[e + 1];
    uint2 ua = *(const uint2*)(hlin + (size_t)s0 * H_DIM + c);
    uint2 ub = *(const uint2*)(hlin + (size_t)s1 * H_DIM + c);
    a0 += w0 * bflo(ua.x) + w1 * bflo(ub.x);
    a1 += w0 * bfhi(ua.x) + w1 * bfhi(ub.x);
    a2 += w0 * bflo(ua.y) + w1 * bflo(ub.y);
    a3 += w0 * bfhi(ua.y) + w1 * bfhi(ub.y);
  }
  if (e < e1){
    int s0 = srcs[e]; float w0 = wts[e];
    uint2 ua = *(const uint2*)(hlin + (size_t)s0 * H_DIM + c);
    a0 += w0 * bflo(ua.x); a1 += w0 * bfhi(ua.x);
    a2 += w0 * bflo(ua.y); a3 += w0 * bfhi(ua.y);
  }
  a0 = fmaxf(a0, 0.f); a1 = fmaxf(a1, 0.f); a2 = fmaxf(a2, 0.f); a3 = fmaxf(a3, 0.f);
  uint2 o; o.x = pack2(a0, a1); o.y = pack2(a2, a3);
  *(uint2*)(g + (size_t)node * H_DIM + c) = o;
}

// ---------------- column stats over g (bf16 [N,256]) ----------------
__global__ __launch_bounds__(256) void colstats_k(const unsigned short* g, float* S, float* Q){
  int t = threadIdx.x;
  int cl = t & 63, rg = t >> 6;
  int c = cl * 4;
  float s0=0,s1=0,s2=0,s3=0,q0=0,q1=0,q2=0,q3=0;
  for (int row = blockIdx.x * 4 + rg; row < N_NODES; row += gridDim.x * 4){
    uint2 u = *(const uint2*)(g + (size_t)row * H_DIM + c);
    float v0 = bflo(u.x), v1 = bfhi(u.x), v2 = bflo(u.y), v3 = bfhi(u.y);
    s0 += v0; s1 += v1; s2 += v2; s3 += v3;
    q0 += v0*v0; q1 += v1*v1; q2 += v2*v2; q3 += v3*v3;
  }
  __shared__ float red[256][8];
  red[t][0]=s0; red[t][1]=s1; red[t][2]=s2; red[t][3]=s3;
  red[t][4]=q0; red[t][5]=q1; red[t][6]=q2; red[t][7]=q3;
  __syncthreads();
  if (t < 64){
    float a[8];
    #pragma unroll
    for (int i = 0; i < 8; ++i) a[i] = red[t][i];
    for (int j = 1; j < 4; ++j)
      #pragma unroll
      for (int i = 0; i < 8; ++i) a[i] += red[t + 64*j][i];
    #pragma unroll
    for (int i = 0; i < 4; ++i){ atomicAdd(&S[t*4+i], a[i]); atomicAdd(&Q[t*4+i], a[4+i]); }
  }
}

__global__ void bnfin_k(const float* S, const float* Q, const float* gg, const float* bb,
                        float* sc, float* sh){
  int c = threadIdx.x; // 256
  float mu = S[c] * (1.0f / N_NODES);
  float var = Q[c] * (1.0f / N_NODES) - mu * mu;
  float rs = rsqrtf(var + BN_EPS);
  sc[c] = gg[c] * rs;
  sh[c] = bb[c] - gg[c] * rs * mu;
}

// ---------------- BN + LN apply (layer 1): h1 = LN(BN(g)) ----------------
__global__ __launch_bounds__(256) void apply1_k(const unsigned short* g, const float* sc, const float* sh,
                                                const float* lng, const float* lnb, unsigned short* h1){
  int lane = threadIdx.x & 63;
  int row = blockIdx.x * 4 + (threadIdx.x >> 6);
  if (row >= N_NODES) return;
  int c = lane * 4;
  uint2 u = *(const uint2*)(g + (size_t)row * H_DIM + c);
  float4 s4 = *(const float4*)(sc + c);
  float4 h4 = *(const float4*)(sh + c);
  float v0 = s4.x * bflo(u.x) + h4.x;
  float v1 = s4.y * bfhi(u.x) + h4.y;
  float v2 = s4.z * bflo(u.y) + h4.z;
  float v3 = s4.w * bfhi(u.y) + h4.w;
  float sum = wred(v0 + v1 + v2 + v3);
  float sq  = wred(v0*v0 + v1*v1 + v2*v2 + v3*v3);
  float mu = sum * (1.0f / H_DIM);
  float var = sq * (1.0f / H_DIM) - mu * mu;
  float rs = rsqrtf(var + LN_EPS);
  float4 g4 = *(const float4*)(lng + c);
  float4 b4 = *(const float4*)(lnb + c);
  float y0 = g4.x * (v0 - mu) * rs + b4.x;
  float y1 = g4.y * (v1 - mu) * rs + b4.y;
  float y2 = g4.z * (v2 - mu) * rs + b4.z;
  float y3 = g4.w * (v3 - mu) * rs + b4.w;
  uint2 o; o.x = pack2(y0, y1); o.y = pack2(y2, y3);
  *(uint2*)(h1 + (size_t)row * H_DIM + c) = o;
}

// ---------------- layer 2 apply + residual + output GEMM ----------------
__global__ __launch_bounds__(256) void apply2_k(const unsigned short* g, const float* sc, const float* sh,
                                                const float* lng, const float* lnb,
                                                const unsigned short* h1, const float* Wout,
                                                const float* bout, float* out){
  int lane = threadIdx.x & 63;
  int row = blockIdx.x * 4 + (threadIdx.x >> 6);
  if (row >= N_NODES) return;
  int c = lane * 4;
  uint2 u = *(const uint2*)(g + (size_t)row * H_DIM + c);
  float4 s4 = *(const float4*)(sc + c);
  float4 h4 = *(const float4*)(sh + c);
  float v0 = s4.x * bflo(u.x) + h4.x;
  float v1 = s4.y * bfhi(u.x) + h4.y;
  float v2 = s4.z * bflo(u.y) + h4.z;
  float v3 = s4.w * bfhi(u.y) + h4.w;
  float sum = wred(v0 + v1 + v2 + v3);
  float sq  = wred(v0*v0 + v1*v1 + v2*v2 + v3*v3);
  float mu = sum * (1.0f / H_DIM);
  float var = sq * (1.0f / H_DIM) - mu * mu;
  float rs = rsqrtf(var + LN_EPS);
  float4 g4 = *(const float4*)(lng + c);
  float4 b4 = *(const float4*)(lnb + c);
  uint2 hr = *(const uint2*)(h1 + (size_t)row * H_DIM + c);
  float y0 = g4.x * (v0 - mu) * rs + b4.x + bflo(hr.x);
  float y1 = g4.y * (v1 - mu) * rs + b4.y + bfhi(hr.x);
  float y2 = g4.z * (v2 - mu) * rs + b4.z + bflo(hr.y);
  float y3 = g4.w * (v3 - mu) * rs + b4.w + bfhi(hr.y);
  // Wout row-major [256][2]
  float4 w0 = *(const float4*)(Wout + c * 2);      // (c,0) (c,1) (c+1,0) (c+1,1)
  float4 w1 = *(const float4*)(Wout + c * 2 + 4);  // (c+2,0) (c+2,1) (c+3,0) (c+3,1)
  float o0 = y0 * w0.x + y1 * w0.z + y2 * w1.x + y3 * w1.z;
  float o1 = y0 * w0.y + y1 * w0.w + y2 * w1.y + y3 * w1.w;
  o0 = wred(o0); o1 = wred(o1);
  if (lane == 0){
    out[(size_t)row * 2 + 0] = o0 + bout[0];
    out[(size_t)row * 2 + 1] = o1 + bout[1];
  }
}

extern "C" void kernel_launch(void* const* d_in, const int* in_sizes, int n_in,
                              void* d_out, int out_size, void* d_ws, size_t ws_size,
                              hipStream_t stream) {
  const float* x    = (const float*)d_in[0];
  const int*   ei   = (const int*)d_in[1];
  const float* fs   = (const float*)d_in[2];
  const float* fb   = (const float*)d_in[3];
  const float* bn0g = (const float*)d_in[4];
  const float* bn0b = (const float*)d_in[5];
  const float* W1   = (const float*)d_in[6];
  const float* b1   = (const float*)d_in[7];
  const float* bn1g = (const float*)d_in[8];
  const float* bn1b = (const float*)d_in[9];
  const float* ln1g = (const float*)d_in[10];
  const float* ln1b = (const float*)d_in[11];
  const float* W2   = (const float*)d_in[12];
  const float* b2   = (const float*)d_in[13];
  const float* bn2g = (const float*)d_in[14];
  const float* bn2b = (const float*)d_in[15];
  const float* ln2g = (const float*)d_in[16];
  const float* ln2b = (const float*)d_in[17];
  const float* Wout = (const float*)d_in[18];
  const float* bout = (const float*)d_in[19];
  float* out = (float*)d_out;

  char* w = (char*)d_ws;
  // zeroed region (one memset): cnt + all stat sums
  int*   cnt   = (int*)(w + 0);            // 200000 B
  float* bn0S  = (float*)(w + 200000);     // 512
  float* bn0Q  = (float*)(w + 200512);     // 512
  float* S1    = (float*)(w + 201024);     // 1024
  float* Q1    = (float*)(w + 202048);     // 1024
  float* S2    = (float*)(w + 203072);     // 1024
  float* Q2    = (float*)(w + 204096);     // 1024 -> end 205120
  const size_t ZERO_BYTES = 205120;
  float* A0    = (float*)(w + 205120);     // 512
  float* B0    = (float*)(w + 205632);     // 512
  float* s1    = (float*)(w + 206144);     // 1024
  float* t1    = (float*)(w + 207168);     // 1024
  float* s2    = (float*)(w + 208192);     // 1024
  float* t2    = (float*)(w + 209216);     // 1024 -> 210240
  int*   bsum  = (int*)(w + 210240);       // 1024 (196 used)
  int*   bpre  = (int*)(w + 211264);       // 1024 (196 used)
  float* dinv  = (float*)(w + 212288);     // 200000 -> 412288
  int*   offs  = (int*)(w + 412288);       // 200004 -> pad to 612352
  int*   curs  = (int*)(w + 612352);       // 200000 -> 812352
  int*   srcs  = (int*)(w + 812352);       // 3200000 -> 4012352
  float* wts   = (float*)(w + 4012352);    // 3200000 -> 7212352
  unsigned short* xt   = (unsigned short*)(w + 7212352);   // 12.8 MB -> 20012352
  unsigned short* W1t  = (unsigned short*)(w + 20012352);  // 64 KB  -> 20077888
  unsigned short* W2t  = (unsigned short*)(w + 20077888);  // 128 KB -> 20208960
  unsigned short* hlin = (unsigned short*)(w + 20208960);  // 25.6 MB -> 45808960
  unsigned short* gbuf = (unsigned short*)(w + 45808960);  // 25.6 MB -> 71408960
  unsigned short* h1   = (unsigned short*)(w + 71408960);  // 25.6 MB -> 97008960

  (void)in_sizes; (void)n_in; (void)out_size; (void)ws_size;

  hipMemsetAsync(d_ws, 0, ZERO_BYTES, stream);

  // graph preprocessing: degree -> device-wide scan (3 stages) -> CSR scatter
  deg_k<<<(N_EDGES + 255) / 256, 256, 0, stream>>>(ei, cnt);
  blocksum_k<<<NBLK_SCAN, 256, 0, stream>>>(cnt, bsum);
  bscan_k<<<1, 256, 0, stream>>>(bsum, bpre, offs);
  cscan_k<<<NBLK_SCAN, 256, 0, stream>>>(cnt, bpre, offs, curs, dinv);
  csr_k<<<(N_EDGES + 255) / 256, 256, 0, stream>>>(ei, dinv, curs, srcs, wts);

  // input transform + BN0 folded into affine, cast to bf16
  bn0stats_k<<<256, 256, 0, stream>>>(x, fs, fb, bn0S, bn0Q);
  bn0final_k<<<1, 128, 0, stream>>>(bn0S, bn0Q, fs, fb, bn0g, bn0b, A0, B0);
  prepx_k<<<(N_NODES * 32) / 256, 256, 0, stream>>>(x, A0, B0, xt);

  // weight transposes (bf16, K-inner), merged
  transpose2_k<<<(H_DIM * H_DIM + 255) / 256, 256, 0, stream>>>(W1, W2, W1t, W2t);

  dim3 ggrid(H_DIM / 64, (N_NODES + 63) / 64);

  // ---- layer 1 ----
  gemm_k<<<ggrid, 256, 0, stream>>>(xt, W1t, hlin, N_NODES, D_IN);
  agg_k<<<(N_NODES + 3) / 4, 256, 0, stream>>>(hlin, offs, srcs, wts, dinv, b1, gbuf);
  colstats_k<<<512, 256, 0, stream>>>(gbuf, S1, Q1);
  bnfin_k<<<1, 256, 0, stream>>>(S1, Q1, bn1g, bn1b, s1, t1);
  apply1_k<<<(N_NODES + 3) / 4, 256, 0, stream>>>(gbuf, s1, t1, ln1g, ln1b, h1);

  // ---- layer 2 ----
  gemm_k<<<ggrid, 256, 0, stream>>>(h1, W2t, hlin, N_NODES, H_DIM);
  agg_k<<<(N_NODES + 3) / 4, 256, 0, stream>>>(hlin, offs, srcs, wts, dinv, b2, gbuf);
  colstats_k<<<512, 256, 0, stream>>>(gbuf, S2, Q2);
  bnfin_k<<<1, 256, 0, stream>>>(S2, Q2, bn2g, bn2b, s2, t2);
  apply2_k<<<(N_NODES + 3) / 4, 256, 0, stream>>>(gbuf, s2, t2, ln2g, ln2b, h1, Wout, bout, out);
}

// Round 3
// 558.832 us; speedup vs baseline: 1.1765x; 1.0064x over previous
//
#include <hip/hip_runtime.h>
#include <hip/hip_bf16.h>
#include <stdint.h>

#define N_NODES 50000
#define N_EDGES 800000
#define D_IN    128
#define H_DIM   256
#define BN_EPS  1e-5f
#define LN_EPS  1e-5f
#define NBLK_SCAN 196  // ceil(50000/256)

typedef float v4f __attribute__((ext_vector_type(4)));
typedef short v8s __attribute__((ext_vector_type(8)));

__device__ __forceinline__ float bflo(unsigned u){ return __uint_as_float(u << 16); }
__device__ __forceinline__ float bfhi(unsigned u){ return __uint_as_float(u & 0xffff0000u); }
__device__ __forceinline__ unsigned short f2bf(float f){
  unsigned u = __float_as_uint(f);
  u += 0x7fffu + ((u >> 16) & 1u);
  return (unsigned short)(u >> 16);
}
__device__ __forceinline__ unsigned pack2(float a, float b){
  return (unsigned)f2bf(a) | ((unsigned)f2bf(b) << 16);
}
__device__ __forceinline__ float wred(float v){
  #pragma unroll
  for (int m = 1; m < 64; m <<= 1) v += __shfl_xor(v, m, 64);
  return v;
}

// in-block (256 threads) exclusive scan of one int per thread
__device__ __forceinline__ int block_excl_scan(int v){
  int t = threadIdx.x;
  int lane = t & 63, w = t >> 6;
  int inc = v;
  #pragma unroll
  for (int m = 1; m < 64; m <<= 1){
    int o = __shfl_up(inc, m, 64);
    if (lane >= m) inc += o;
  }
  __shared__ int wsum[4];
  if (lane == 63) wsum[w] = inc;
  __syncthreads();
  int base = 0;
  #pragma unroll
  for (int j = 0; j < 4; ++j) if (j < w) base += wsum[j];
  return base + inc - v;  // exclusive
}

// ---------------- degree / CSR ----------------
__global__ void deg_k(const int* ei, int* cnt){
  int e = blockIdx.x * 256 + threadIdx.x;
  if (e < N_EDGES) atomicAdd(&cnt[ei[N_EDGES + e]], 1);
}

__global__ __launch_bounds__(256) void blocksum_k(const int* cnt, int* bsum){
  int i = blockIdx.x * 256 + threadIdx.x;
  int v = (i < N_NODES) ? cnt[i] : 0;
  #pragma unroll
  for (int m = 1; m < 64; m <<= 1) v += __shfl_xor(v, m, 64);
  __shared__ int ws[4];
  int t = threadIdx.x;
  if ((t & 63) == 0) ws[t >> 6] = v;
  __syncthreads();
  if (t == 0) bsum[blockIdx.x] = ws[0] + ws[1] + ws[2] + ws[3];
}

__global__ __launch_bounds__(256) void bscan_k(const int* bsum, int* bpre, int* offs){
  int t = threadIdx.x;
  int v = (t < NBLK_SCAN) ? bsum[t] : 0;
  int e = block_excl_scan(v);
  if (t < NBLK_SCAN) bpre[t] = e;
  if (t == 0) offs[N_NODES] = N_EDGES;
}

__global__ __launch_bounds__(256) void cscan_k(const int* cnt, const int* bpre,
                                               int* offs, int* curs, float* dinv){
  int i = blockIdx.x * 256 + threadIdx.x;
  int v = (i < N_NODES) ? cnt[i] : 0;
  int e = block_excl_scan(v) + bpre[blockIdx.x];
  if (i < N_NODES){
    offs[i] = e; curs[i] = e;
    dinv[i] = rsqrtf((float)v + 1.0f);
  }
}

__global__ void csr_k(const int* ei, const float* dinv, int* cursor, uint2* edges){
  int e = blockIdx.x * 256 + threadIdx.x;
  if (e >= N_EDGES) return;
  int s = ei[e], d = ei[N_EDGES + e];
  int p = atomicAdd(&cursor[d], 1);
  uint2 pk;
  pk.x = (unsigned)s;
  pk.y = __float_as_uint(dinv[s] * dinv[d]);
  edges[p] = pk;
}

// ---------------- BN0 stats over y = x*fs + fb ----------------
__global__ __launch_bounds__(256) void bn0stats_k(const float* x, const float* fs, const float* fb,
                                                  float* S, float* Q){
  int t = threadIdx.x;
  int cl = t & 31, rg = t >> 5;
  int c = cl * 4;
  float4 fs4 = *(const float4*)(fs + c);
  float4 fb4 = *(const float4*)(fb + c);
  float s0=0,s1=0,s2=0,s3=0,q0=0,q1=0,q2=0,q3=0;
  for (int row = blockIdx.x * 8 + rg; row < N_NODES; row += gridDim.x * 8){
    float4 xv = *(const float4*)(x + (size_t)row * D_IN + c);
    float v0 = xv.x * fs4.x + fb4.x;
    float v1 = xv.y * fs4.y + fb4.y;
    float v2 = xv.z * fs4.z + fb4.z;
    float v3 = xv.w * fs4.w + fb4.w;
    s0 += v0; s1 += v1; s2 += v2; s3 += v3;
    q0 += v0*v0; q1 += v1*v1; q2 += v2*v2; q3 += v3*v3;
  }
  __shared__ float red[256][8];
  red[t][0]=s0; red[t][1]=s1; red[t][2]=s2; red[t][3]=s3;
  red[t][4]=q0; red[t][5]=q1; red[t][6]=q2; red[t][7]=q3;
  __syncthreads();
  if (t < 32){
    float a[8];
    #pragma unroll
    for (int i = 0; i < 8; ++i) a[i] = red[t][i];
    for (int j = 1; j < 8; ++j)
      #pragma unroll
      for (int i = 0; i < 8; ++i) a[i] += red[t + 32*j][i];
    #pragma unroll
    for (int i = 0; i < 4; ++i){ atomicAdd(&S[t*4+i], a[i]); atomicAdd(&Q[t*4+i], a[4+i]); }
  }
}

// prepx with BN0 finalization fused: per-thread recompute of affine from stats
__global__ __launch_bounds__(256) void prepx_k(const float* x, const float* S, const float* Q,
                                               const float* fs, const float* fb,
                                               const float* gg, const float* bb,
                                               unsigned short* xt){
  int i = blockIdx.x * 256 + threadIdx.x; // N*32 total
  int row = i >> 5; int c = (i & 31) * 4;
  float4 Sv = *(const float4*)(S + c);
  float4 Qv = *(const float4*)(Q + c);
  float4 fs4 = *(const float4*)(fs + c);
  float4 fb4 = *(const float4*)(fb + c);
  float4 gg4 = *(const float4*)(gg + c);
  float4 bb4 = *(const float4*)(bb + c);
  const float invN = 1.0f / N_NODES;
  float mu0 = Sv.x*invN, mu1 = Sv.y*invN, mu2 = Sv.z*invN, mu3 = Sv.w*invN;
  float r0 = rsqrtf(Qv.x*invN - mu0*mu0 + BN_EPS);
  float r1 = rsqrtf(Qv.y*invN - mu1*mu1 + BN_EPS);
  float r2 = rsqrtf(Qv.z*invN - mu2*mu2 + BN_EPS);
  float r3 = rsqrtf(Qv.w*invN - mu3*mu3 + BN_EPS);
  float a0 = gg4.x*r0*fs4.x, b0 = gg4.x*r0*(fb4.x - mu0) + bb4.x;
  float a1 = gg4.y*r1*fs4.y, b1 = gg4.y*r1*(fb4.y - mu1) + bb4.y;
  float a2 = gg4.z*r2*fs4.z, b2 = gg4.z*r2*(fb4.z - mu2) + bb4.z;
  float a3 = gg4.w*r3*fs4.w, b3 = gg4.w*r3*(fb4.w - mu3) + bb4.w;
  float4 xv = *(const float4*)(x + (size_t)row * D_IN + c);
  uint2 o;
  o.x = pack2(a0 * xv.x + b0, a1 * xv.y + b1);
  o.y = pack2(a2 * xv.z + b2, a3 * xv.w + b3);
  *(uint2*)(xt + (size_t)row * D_IN + c) = o;
}

__global__ void transpose2_k(const float* W1, const float* W2,
                             unsigned short* W1t, unsigned short* W2t){
  int i = blockIdx.x * 256 + threadIdx.x;
  if (i < D_IN * H_DIM){
    int r = i / H_DIM, c = i % H_DIM;
    W1t[c * D_IN + r] = f2bf(W1[i]);
  }
  if (i < H_DIM * H_DIM){
    int r = i / H_DIM, c = i % H_DIM;
    W2t[c * H_DIM + r] = f2bf(W2[i]);
  }
}

// ---------------- bf16 MFMA GEMM: C[M,256] = A[M,K] @ Bt[256,K]^T ----------------
template<int K>
__global__ __launch_bounds__(256) void gemm_k(const unsigned short* A, const unsigned short* Bt,
                                              unsigned short* C, int M){
  __shared__ __align__(16) short As[64 * 40];
  __shared__ __align__(16) short Bs[64 * 40];
  int t = threadIdx.x;
  int m0 = blockIdx.y * 64;
  int n0 = blockIdx.x * 64;
  int lr = t >> 2;
  int lk = (t & 3) << 3;
  int lane = t & 63;
  int w = t >> 6;
  int wm = (w >> 1) << 5, wn = (w & 1) << 5;
  int fr = lane & 15, quad = lane >> 4;
  v4f acc[2][2] = {};
  #pragma unroll
  for (int k0 = 0; k0 < K; k0 += 32){
    __syncthreads();
    uint4 av = {0,0,0,0};
    int row = m0 + lr;
    if (row < M) av = *(const uint4*)(A + (size_t)row * K + k0 + lk);
    *(uint4*)(&As[lr * 40 + lk]) = av;
    uint4 bv = *(const uint4*)(Bt + (size_t)(n0 + lr) * K + k0 + lk);
    *(uint4*)(&Bs[lr * 40 + lk]) = bv;
    __syncthreads();
    v8s a0 = *(const v8s*)(&As[(wm + fr) * 40 + quad * 8]);
    v8s a1 = *(const v8s*)(&As[(wm + 16 + fr) * 40 + quad * 8]);
    v8s b0 = *(const v8s*)(&Bs[(wn + fr) * 40 + quad * 8]);
    v8s b1 = *(const v8s*)(&Bs[(wn + 16 + fr) * 40 + quad * 8]);
    acc[0][0] = __builtin_amdgcn_mfma_f32_16x16x32_bf16(a0, b0, acc[0][0], 0, 0, 0);
    acc[0][1] = __builtin_amdgcn_mfma_f32_16x16x32_bf16(a0, b1, acc[0][1], 0, 0, 0);
    acc[1][0] = __builtin_amdgcn_mfma_f32_16x16x32_bf16(a1, b0, acc[1][0], 0, 0, 0);
    acc[1][1] = __builtin_amdgcn_mfma_f32_16x16x32_bf16(a1, b1, acc[1][1], 0, 0, 0);
  }
  #pragma unroll
  for (int ti = 0; ti < 2; ++ti)
    #pragma unroll
    for (int tj = 0; tj < 2; ++tj)
      #pragma unroll
      for (int r = 0; r < 4; ++r){
        int row = m0 + wm + ti * 16 + quad * 4 + r;
        if (row < M){
          int col = n0 + wn + tj * 16 + fr;
          C[(size_t)row * H_DIM + col] = f2bf(acc[ti][tj][r]);
        }
      }
}

// ---------------- edge aggregation: g = relu(sum_e w*hlin[src] + dinv^2*hlin[node] + b) ----------------
__global__ __launch_bounds__(256) void agg_k(const unsigned short* hlin, const int* offsets,
                                             const uint2* edges, const float* dinv,
                                             const float* bias, unsigned short* g){
  int lane = threadIdx.x & 63;
  int node = __builtin_amdgcn_readfirstlane(blockIdx.x * 4 + (threadIdx.x >> 6));
  if (node >= N_NODES) return;
  int c = lane * 4;
  float4 bb = *(const float4*)(bias + c);
  float di = dinv[node]; float dii = di * di;
  uint2 u = *(const uint2*)(hlin + (size_t)node * H_DIM + c);
  float a0 = bb.x + dii * bflo(u.x);
  float a1 = bb.y + dii * bfhi(u.x);
  float a2 = bb.z + dii * bflo(u.y);
  float a3 = bb.w + dii * bfhi(u.y);
  int e  = __builtin_amdgcn_readfirstlane(offsets[node]);
  int e1 = __builtin_amdgcn_readfirstlane(offsets[node + 1]);
  for (; e + 4 <= e1; e += 4){
    uint2 p0 = edges[e], p1 = edges[e+1], p2 = edges[e+2], p3 = edges[e+3];
    uint2 ua = *(const uint2*)(hlin + (size_t)p0.x * H_DIM + c);
    uint2 ub = *(const uint2*)(hlin + (size_t)p1.x * H_DIM + c);
    uint2 uc = *(const uint2*)(hlin + (size_t)p2.x * H_DIM + c);
    uint2 ud = *(const uint2*)(hlin + (size_t)p3.x * H_DIM + c);
    float w0 = __uint_as_float(p0.y), w1 = __uint_as_float(p1.y);
    float w2 = __uint_as_float(p2.y), w3 = __uint_as_float(p3.y);
    a0 += w0 * bflo(ua.x) + w1 * bflo(ub.x) + w2 * bflo(uc.x) + w3 * bflo(ud.x);
    a1 += w0 * bfhi(ua.x) + w1 * bfhi(ub.x) + w2 * bfhi(uc.x) + w3 * bfhi(ud.x);
    a2 += w0 * bflo(ua.y) + w1 * bflo(ub.y) + w2 * bflo(uc.y) + w3 * bflo(ud.y);
    a3 += w0 * bfhi(ua.y) + w1 * bfhi(ub.y) + w2 * bfhi(uc.y) + w3 * bfhi(ud.y);
  }
  for (; e < e1; ++e){
    uint2 p0 = edges[e];
    uint2 ua = *(const uint2*)(hlin + (size_t)p0.x * H_DIM + c);
    float w0 = __uint_as_float(p0.y);
    a0 += w0 * bflo(ua.x); a1 += w0 * bfhi(ua.x);
    a2 += w0 * bflo(ua.y); a3 += w0 * bfhi(ua.y);
  }
  a0 = fmaxf(a0, 0.f); a1 = fmaxf(a1, 0.f); a2 = fmaxf(a2, 0.f); a3 = fmaxf(a3, 0.f);
  uint2 o; o.x = pack2(a0, a1); o.y = pack2(a2, a3);
  *(uint2*)(g + (size_t)node * H_DIM + c) = o;
}

// ---------------- column stats over g (bf16 [N,256]) ----------------
__global__ __launch_bounds__(256) void colstats_k(const unsigned short* g, float* S, float* Q){
  int t = threadIdx.x;
  int cl = t & 63, rg = t >> 6;
  int c = cl * 4;
  float s0=0,s1=0,s2=0,s3=0,q0=0,q1=0,q2=0,q3=0;
  for (int row = blockIdx.x * 4 + rg; row < N_NODES; row += gridDim.x * 4){
    uint2 u = *(const uint2*)(g + (size_t)row * H_DIM + c);
    float v0 = bflo(u.x), v1 = bfhi(u.x), v2 = bflo(u.y), v3 = bfhi(u.y);
    s0 += v0; s1 += v1; s2 += v2; s3 += v3;
    q0 += v0*v0; q1 += v1*v1; q2 += v2*v2; q3 += v3*v3;
  }
  __shared__ float red[256][8];
  red[t][0]=s0; red[t][1]=s1; red[t][2]=s2; red[t][3]=s3;
  red[t][4]=q0; red[t][5]=q1; red[t][6]=q2; red[t][7]=q3;
  __syncthreads();
  if (t < 64){
    float a[8];
    #pragma unroll
    for (int i = 0; i < 8; ++i) a[i] = red[t][i];
    for (int j = 1; j < 4; ++j)
      #pragma unroll
      for (int i = 0; i < 8; ++i) a[i] += red[t + 64*j][i];
    #pragma unroll
    for (int i = 0; i < 4; ++i){ atomicAdd(&S[t*4+i], a[i]); atomicAdd(&Q[t*4+i], a[4+i]); }
  }
}

// per-thread BN finalize from raw stats (S,Q) for this thread's 4 columns
__device__ __forceinline__ void bn_coeffs(const float* S, const float* Q,
                                          const float* gg, const float* bb, int c,
                                          float4& sc, float4& sh){
  float4 Sv = *(const float4*)(S + c);
  float4 Qv = *(const float4*)(Q + c);
  float4 g4 = *(const float4*)(gg + c);
  float4 b4 = *(const float4*)(bb + c);
  const float invN = 1.0f / N_NODES;
  float mu0 = Sv.x*invN, mu1 = Sv.y*invN, mu2 = Sv.z*invN, mu3 = Sv.w*invN;
  sc.x = g4.x * rsqrtf(Qv.x*invN - mu0*mu0 + BN_EPS);
  sc.y = g4.y * rsqrtf(Qv.y*invN - mu1*mu1 + BN_EPS);
  sc.z = g4.z * rsqrtf(Qv.z*invN - mu2*mu2 + BN_EPS);
  sc.w = g4.w * rsqrtf(Qv.w*invN - mu3*mu3 + BN_EPS);
  sh.x = b4.x - sc.x * mu0; sh.y = b4.y - sc.y * mu1;
  sh.z = b4.z - sc.z * mu2; sh.w = b4.w - sc.w * mu3;
}

// ---------------- BN + LN apply (layer 1): h1 = LN(BN(g)) ----------------
__global__ __launch_bounds__(256) void apply1_k(const unsigned short* g, const float* S, const float* Q,
                                                const float* bng, const float* bnb,
                                                const float* lng, const float* lnb, unsigned short* h1){
  int lane = threadIdx.x & 63;
  int row = blockIdx.x * 4 + (threadIdx.x >> 6);
  if (row >= N_NODES) return;
  int c = lane * 4;
  float4 s4, h4;
  bn_coeffs(S, Q, bng, bnb, c, s4, h4);
  uint2 u = *(const uint2*)(g + (size_t)row * H_DIM + c);
  float v0 = s4.x * bflo(u.x) + h4.x;
  float v1 = s4.y * bfhi(u.x) + h4.y;
  float v2 = s4.z * bflo(u.y) + h4.z;
  float v3 = s4.w * bfhi(u.y) + h4.w;
  float sum = wred(v0 + v1 + v2 + v3);
  float sq  = wred(v0*v0 + v1*v1 + v2*v2 + v3*v3);
  float mu = sum * (1.0f / H_DIM);
  float var = sq * (1.0f / H_DIM) - mu * mu;
  float rs = rsqrtf(var + LN_EPS);
  float4 g4 = *(const float4*)(lng + c);
  float4 b4 = *(const float4*)(lnb + c);
  float y0 = g4.x * (v0 - mu) * rs + b4.x;
  float y1 = g4.y * (v1 - mu) * rs + b4.y;
  float y2 = g4.z * (v2 - mu) * rs + b4.z;
  float y3 = g4.w * (v3 - mu) * rs + b4.w;
  uint2 o; o.x = pack2(y0, y1); o.y = pack2(y2, y3);
  *(uint2*)(h1 + (size_t)row * H_DIM + c) = o;
}

// ---------------- layer 2 apply + residual + output GEMM ----------------
__global__ __launch_bounds__(256) void apply2_k(const unsigned short* g, const float* S, const float* Q,
                                                const float* bng, const float* bnb,
                                                const float* lng, const float* lnb,
                                                const unsigned short* h1, const float* Wout,
                                                const float* bout, float* out){
  int lane = threadIdx.x & 63;
  int row = blockIdx.x * 4 + (threadIdx.x >> 6);
  if (row >= N_NODES) return;
  int c = lane * 4;
  float4 s4, h4;
  bn_coeffs(S, Q, bng, bnb, c, s4, h4);
  uint2 u = *(const uint2*)(g + (size_t)row * H_DIM + c);
  float v0 = s4.x * bflo(u.x) + h4.x;
  float v1 = s4.y * bfhi(u.x) + h4.y;
  float v2 = s4.z * bflo(u.y) + h4.z;
  float v3 = s4.w * bfhi(u.y) + h4.w;
  float sum = wred(v0 + v1 + v2 + v3);
  float sq  = wred(v0*v0 + v1*v1 + v2*v2 + v3*v3);
  float mu = sum * (1.0f / H_DIM);
  float var = sq * (1.0f / H_DIM) - mu * mu;
  float rs = rsqrtf(var + LN_EPS);
  float4 g4 = *(const float4*)(lng + c);
  float4 b4 = *(const float4*)(lnb + c);
  uint2 hr = *(const uint2*)(h1 + (size_t)row * H_DIM + c);
  float y0 = g4.x * (v0 - mu) * rs + b4.x + bflo(hr.x);
  float y1 = g4.y * (v1 - mu) * rs + b4.y + bfhi(hr.x);
  float y2 = g4.z * (v2 - mu) * rs + b4.z + bflo(hr.y);
  float y3 = g4.w * (v3 - mu) * rs + b4.w + bfhi(hr.y);
  // Wout row-major [256][2]
  float4 w0 = *(const float4*)(Wout + c * 2);      // (c,0) (c,1) (c+1,0) (c+1,1)
  float4 w1 = *(const float4*)(Wout + c * 2 + 4);  // (c+2,0) (c+2,1) (c+3,0) (c+3,1)
  float o0 = y0 * w0.x + y1 * w0.z + y2 * w1.x + y3 * w1.z;
  float o1 = y0 * w0.y + y1 * w0.w + y2 * w1.y + y3 * w1.w;
  o0 = wred(o0); o1 = wred(o1);
  if (lane == 0){
    out[(size_t)row * 2 + 0] = o0 + bout[0];
    out[(size_t)row * 2 + 1] = o1 + bout[1];
  }
}

extern "C" void kernel_launch(void* const* d_in, const int* in_sizes, int n_in,
                              void* d_out, int out_size, void* d_ws, size_t ws_size,
                              hipStream_t stream) {
  const float* x    = (const float*)d_in[0];
  const int*   ei   = (const int*)d_in[1];
  const float* fs   = (const float*)d_in[2];
  const float* fb   = (const float*)d_in[3];
  const float* bn0g = (const float*)d_in[4];
  const float* bn0b = (const float*)d_in[5];
  const float* W1   = (const float*)d_in[6];
  const float* b1   = (const float*)d_in[7];
  const float* bn1g = (const float*)d_in[8];
  const float* bn1b = (const float*)d_in[9];
  const float* ln1g = (const float*)d_in[10];
  const float* ln1b = (const float*)d_in[11];
  const float* W2   = (const float*)d_in[12];
  const float* b2   = (const float*)d_in[13];
  const float* bn2g = (const float*)d_in[14];
  const float* bn2b = (const float*)d_in[15];
  const float* ln2g = (const float*)d_in[16];
  const float* ln2b = (const float*)d_in[17];
  const float* Wout = (const float*)d_in[18];
  const float* bout = (const float*)d_in[19];
  float* out = (float*)d_out;

  char* w = (char*)d_ws;
  // zeroed region (one memset): cnt + all stat sums
  int*   cnt   = (int*)(w + 0);            // 200000 B
  float* bn0S  = (float*)(w + 200000);     // 512
  float* bn0Q  = (float*)(w + 200512);     // 512
  float* S1    = (float*)(w + 201024);     // 1024
  float* Q1    = (float*)(w + 202048);     // 1024
  float* S2    = (float*)(w + 203072);     // 1024
  float* Q2    = (float*)(w + 204096);     // 1024 -> end 205120
  const size_t ZERO_BYTES = 205120;
  int*   bsum  = (int*)(w + 205120);       // 1024 (196 used)
  int*   bpre  = (int*)(w + 206144);       // 1024 (196 used)
  float* dinv  = (float*)(w + 207168);     // 200000 -> 407168
  int*   offs  = (int*)(w + 407168);       // 200004 -> pad to 607232
  int*   curs  = (int*)(w + 607232);       // 200000 -> 807232
  uint2* edges = (uint2*)(w + 807232);     // 6400000 -> 7207232
  unsigned short* xt   = (unsigned short*)(w + 7207232);   // 12.8 MB -> 20007232
  unsigned short* W1t  = (unsigned short*)(w + 20007232);  // 64 KB  -> 20072768
  unsigned short* W2t  = (unsigned short*)(w + 20072768);  // 128 KB -> 20203840
  unsigned short* hlin = (unsigned short*)(w + 20203840);  // 25.6 MB -> 45803840
  unsigned short* gbuf = (unsigned short*)(w + 45803840);  // 25.6 MB -> 71403840
  unsigned short* h1   = (unsigned short*)(w + 71403840);  // 25.6 MB -> 97003840

  (void)in_sizes; (void)n_in; (void)out_size; (void)ws_size;

  hipMemsetAsync(d_ws, 0, ZERO_BYTES, stream);

  // graph preprocessing: degree -> device-wide scan (3 stages) -> CSR scatter
  deg_k<<<(N_EDGES + 255) / 256, 256, 0, stream>>>(ei, cnt);
  blocksum_k<<<NBLK_SCAN, 256, 0, stream>>>(cnt, bsum);
  bscan_k<<<1, 256, 0, stream>>>(bsum, bpre, offs);
  cscan_k<<<NBLK_SCAN, 256, 0, stream>>>(cnt, bpre, offs, curs, dinv);
  csr_k<<<(N_EDGES + 255) / 256, 256, 0, stream>>>(ei, dinv, curs, edges);

  // input transform + BN0 folded into affine, cast to bf16 (finalize fused in prepx)
  bn0stats_k<<<256, 256, 0, stream>>>(x, fs, fb, bn0S, bn0Q);
  prepx_k<<<(N_NODES * 32) / 256, 256, 0, stream>>>(x, bn0S, bn0Q, fs, fb, bn0g, bn0b, xt);

  // weight transposes (bf16, K-inner), merged
  transpose2_k<<<(H_DIM * H_DIM + 255) / 256, 256, 0, stream>>>(W1, W2, W1t, W2t);

  dim3 ggrid(H_DIM / 64, (N_NODES + 63) / 64);

  // ---- layer 1 ----
  gemm_k<D_IN><<<ggrid, 256, 0, stream>>>(xt, W1t, hlin, N_NODES);
  agg_k<<<(N_NODES + 3) / 4, 256, 0, stream>>>(hlin, offs, edges, dinv, b1, gbuf);
  colstats_k<<<512, 256, 0, stream>>>(gbuf, S1, Q1);
  apply1_k<<<(N_NODES + 3) / 4, 256, 0, stream>>>(gbuf, S1, Q1, bn1g, bn1b, ln1g, ln1b, h1);

  // ---- layer 2 ----
  gemm_k<H_DIM><<<ggrid, 256, 0, stream>>>(h1, W2t, hlin, N_NODES);
  agg_k<<<(N_NODES + 3) / 4, 256, 0, stream>>>(hlin, offs, edges, dinv, b2, gbuf);
  colstats_k<<<512, 256, 0, stream>>>(gbuf, S2, Q2);
  apply2_k<<<(N_NODES + 3) / 4, 256, 0, stream>>>(gbuf, S2, Q2, bn2g, bn2b, ln2g, ln2b, h1, Wout, bout, out);
}